// Round 8
// baseline (18.934 us; speedup 1.0000x reference)
//
#include <hip/hip_runtime.h>

namespace {
constexpr int kB   = 2;
constexpr int kC   = 64;
constexpr int kH   = 128;
constexpr int kW   = 240;
constexpr int kD0  = 16;          // disps 0,3,...,45
constexpr int kD1  = 5;           // disps -2,-1,0,1,2
constexpr int kWc1 = 285;
constexpr int kWc2 = 242;
constexpr int kPad = 48;          // left pad (>= max disp 45)
constexpr int kRow = 336;         // dwords per cpair row (48 pad |240 data |48 pad)
constexpr int kCP  = 32;          // channel pairs (64 channels)
constexpr int kGroups   = 3;      // cpair-parallel groups {11,11,10}
constexpr int kGThreads = 320;
constexpr int kThreads  = kGroups * kGThreads;  // 960 = 15 waves
constexpr int kAcc  = kD0 + kD1;  // 21
constexpr int kRStr = kWc1 * kAcc;             // 5985 floats per partial slot
constexpr int kOut1 = kB * kD0 * kH * kWc1;
constexpr int kN1   = kD0 * kWc1;              // 4560
constexpr int kN2   = kD1 * kWc2;              // 1210
typedef unsigned int v2u __attribute__((ext_vector_type(2)));
__device__ __forceinline__ float LOF(unsigned int x) {
  return __uint_as_float(x << 16);            // bf16 lo -> f32
}
__device__ __forceinline__ float HIF(unsigned int x) {
  return __uint_as_float(x & 0xffff0000u);    // bf16 hi -> f32
}
__device__ __forceinline__ unsigned int pk2(float lo, float hi) {
  unsigned int r;
  asm("v_cvt_pk_bf16_f32 %0, %1, %2" : "=v"(r) : "v"(lo), "v"(hi));
  return r;
}
}

__global__ __launch_bounds__(kThreads, 4)
void anynet_disp_kernel(const float* __restrict__ fr, float* __restrict__ out) {
  __shared__ unsigned int E[kCP * kRow];  // bf16x2 exp(feat_r): ch 2cp | 2cp+1
  __shared__ float P[kGroups * kRStr];    // dedicated partial slots
  const int bh  = blockIdx.x;             // 0..255
  const int b   = bh >> 7;
  const int h   = bh & 127;
  const int tid = threadIdx.x;

  // ---- phase A0: pads = bf16(1.0)x2 (= exp(0), "invalid disparity")
  for (int i = tid; i < kCP * 24; i += kThreads) {
    const int cp = i / 24, q = i % 24;
    const int j4 = (q < 12) ? q : q + 60;   // uint4 idx: [0,12) and [72,84)
    const uint4 ones = {0x3F803F80u, 0x3F803F80u, 0x3F803F80u, 0x3F803F80u};
    *reinterpret_cast<uint4*>(&E[cp * kRow + 4 * j4]) = ones;
  }
  // ---- phase A1: stage exp as packed bf16 channel-pairs (1920 items)
  const float* fr_b = fr + (size_t)b * kC * kH * kW + (size_t)h * kW;
  for (int i = tid; i < kCP * 60; i += kThreads) {
    const int cp = i / 60, xq = i % 60;
    const float4 v0 = *reinterpret_cast<const float4*>(
        fr_b + (size_t)(2 * cp) * (kH * kW) + 4 * xq);
    const float4 v1 = *reinterpret_cast<const float4*>(
        fr_b + (size_t)(2 * cp + 1) * (kH * kW) + 4 * xq);
    uint4 pk;
    pk.x = pk2(__expf(v0.x), __expf(v1.x));
    pk.y = pk2(__expf(v0.y), __expf(v1.y));
    pk.z = pk2(__expf(v0.z), __expf(v1.z));
    pk.w = pk2(__expf(v0.w), __expf(v1.w));
    *reinterpret_cast<uint4*>(&E[cp * kRow + kPad + 4 * xq]) = pk;
  }
  __syncthreads();

  // ---- phase B: group g owns a cpair slice; thread col t. Same 10
  // ds_read2_b32 tap pattern as R7, but each dword = 2 channels.
  const int g = tid / kGThreads;      // 0..2
  const int t = tid % kGThreads;
  float acc1[kD0] = {};
  float acc2[kD1] = {};
  if (t < kWc1) {
    const int cbeg = (g == 0) ? 0 : (g == 1 ? 11 : 22);
    const int clen = (g < 2) ? 11 : 10;
    unsigned int addr = (unsigned int)(uintptr_t)(const void*)&E[cbeg * kRow + t + 3];
    for (int cc = 0; cc < clen; ++cc) {
      v2u p0, p1, p2, p3, p4, p5, p6, p7, q0, q1;
      asm volatile(
          "ds_read2_b32 %0, %10 offset0:45 offset1:42\n\t"
          "ds_read2_b32 %1, %10 offset0:39 offset1:36\n\t"
          "ds_read2_b32 %2, %10 offset0:33 offset1:30\n\t"
          "ds_read2_b32 %3, %10 offset0:27 offset1:24\n\t"
          "ds_read2_b32 %4, %10 offset0:21 offset1:18\n\t"
          "ds_read2_b32 %5, %10 offset0:15 offset1:12\n\t"
          "ds_read2_b32 %6, %10 offset0:9 offset1:6\n\t"
          "ds_read2_b32 %7, %10 offset0:3 offset1:0\n\t"
          "ds_read2_b32 %8, %10 offset0:43 offset1:44\n\t"
          "ds_read2_b32 %9, %10 offset0:46 offset1:47\n\t"
          "s_waitcnt lgkmcnt(0)"
          : "=&v"(p0), "=&v"(p1), "=&v"(p2), "=&v"(p3), "=&v"(p4),
            "=&v"(p5), "=&v"(p6), "=&v"(p7), "=&v"(q0), "=&v"(q1)
          : "v"(addr));
      // D0 denominators for both channels (tap k at p_{k/2}.{x:even,y:odd})
      const float sl =
          (((LOF(p0.x) + LOF(p0.y)) + (LOF(p1.x) + LOF(p1.y))) +
           ((LOF(p2.x) + LOF(p2.y)) + (LOF(p3.x) + LOF(p3.y)))) +
          (((LOF(p4.x) + LOF(p4.y)) + (LOF(p5.x) + LOF(p5.y))) +
           ((LOF(p6.x) + LOF(p6.y)) + (LOF(p7.x) + LOF(p7.y))));
      const float sh =
          (((HIF(p0.x) + HIF(p0.y)) + (HIF(p1.x) + HIF(p1.y))) +
           ((HIF(p2.x) + HIF(p2.y)) + (HIF(p3.x) + HIF(p3.y)))) +
          (((HIF(p4.x) + HIF(p4.y)) + (HIF(p5.x) + HIF(p5.y))) +
           ((HIF(p6.x) + HIF(p6.y)) + (HIF(p7.x) + HIF(p7.y))));
      const float rl = __builtin_amdgcn_rcpf(sl);
      const float rh = __builtin_amdgcn_rcpf(sh);
      acc1[0]  = fmaf(LOF(p0.x), rl, fmaf(HIF(p0.x), rh, acc1[0]));
      acc1[1]  = fmaf(LOF(p0.y), rl, fmaf(HIF(p0.y), rh, acc1[1]));
      acc1[2]  = fmaf(LOF(p1.x), rl, fmaf(HIF(p1.x), rh, acc1[2]));
      acc1[3]  = fmaf(LOF(p1.y), rl, fmaf(HIF(p1.y), rh, acc1[3]));
      acc1[4]  = fmaf(LOF(p2.x), rl, fmaf(HIF(p2.x), rh, acc1[4]));
      acc1[5]  = fmaf(LOF(p2.y), rl, fmaf(HIF(p2.y), rh, acc1[5]));
      acc1[6]  = fmaf(LOF(p3.x), rl, fmaf(HIF(p3.x), rh, acc1[6]));
      acc1[7]  = fmaf(LOF(p3.y), rl, fmaf(HIF(p3.y), rh, acc1[7]));
      acc1[8]  = fmaf(LOF(p4.x), rl, fmaf(HIF(p4.x), rh, acc1[8]));
      acc1[9]  = fmaf(LOF(p4.y), rl, fmaf(HIF(p4.y), rh, acc1[9]));
      acc1[10] = fmaf(LOF(p5.x), rl, fmaf(HIF(p5.x), rh, acc1[10]));
      acc1[11] = fmaf(LOF(p5.y), rl, fmaf(HIF(p5.y), rh, acc1[11]));
      acc1[12] = fmaf(LOF(p6.x), rl, fmaf(HIF(p6.x), rh, acc1[12]));
      acc1[13] = fmaf(LOF(p6.y), rl, fmaf(HIF(p6.y), rh, acc1[13]));
      acc1[14] = fmaf(LOF(p7.x), rl, fmaf(HIF(p7.x), rh, acc1[14]));
      acc1[15] = fmaf(LOF(p7.y), rl, fmaf(HIF(p7.y), rh, acc1[15]));
      // D1: u[j] = col t+50-j -> offs 47(q1.y),46(q1.x),45(p0.x),44(q0.y),43(q0.x)
      const float s2l = ((LOF(q0.x) + LOF(q0.y)) + (LOF(q1.x) + LOF(q1.y))) + LOF(p0.x);
      const float s2h = ((HIF(q0.x) + HIF(q0.y)) + (HIF(q1.x) + HIF(q1.y))) + HIF(p0.x);
      const float r2l = __builtin_amdgcn_rcpf(s2l);
      const float r2h = __builtin_amdgcn_rcpf(s2h);
      acc2[0] = fmaf(LOF(q1.y), r2l, fmaf(HIF(q1.y), r2h, acc2[0]));
      acc2[1] = fmaf(LOF(q1.x), r2l, fmaf(HIF(q1.x), r2h, acc2[1]));
      acc2[2] = fmaf(LOF(p0.x), r2l, fmaf(HIF(p0.x), r2h, acc2[2]));
      acc2[3] = fmaf(LOF(q0.y), r2l, fmaf(HIF(q0.y), r2h, acc2[3]));
      acc2[4] = fmaf(LOF(q0.x), r2l, fmaf(HIF(q0.x), r2h, acc2[4]));
      addr += kRow * 4;
    }
  }
  __syncthreads();

  // ---- phase C: each group writes its OWN slot (disjoint, proven)
  if (t < kWc1) {
    float* __restrict__ R = &P[g * kRStr + t * kAcc];  // stride 21: conflict-free
    #pragma unroll
    for (int k = 0; k < kD0; ++k) R[k] = acc1[k];
    #pragma unroll
    for (int j = 0; j < kD1; ++j) R[kD0 + j] = acc2[j];
  }
  __syncthreads();

  // ---- phase D: combine 3 slots, coalesced writes (proven)
  for (int i = tid; i < kN1 + kN2; i += kThreads) {
    if (i < kN1) {
      const int d   = i / kWc1;
      const int col = i % kWc1;
      const int o   = col * kAcc + d;
      const float v = P[o] + P[kRStr + o] + P[2 * kRStr + o];
      out[((b * kD0 + d) * kH + h) * kWc1 + col] =
          (3.0f * (float)d) * (4.0f + v);              // C/D0 = 4
    } else {
      const int i2  = i - kN1;
      const int j   = i2 / kWc2;
      const int col = i2 % kWc2;
      const int o   = col * kAcc + kD0 + j;
      const float v = P[o] + P[kRStr + o] + P[2 * kRStr + o];
      out[kOut1 + ((b * kD1 + j) * kH + h) * kWc2 + col] =
          (float)(j - 2) * (64.0f / 5.0f + v);         // C/D1 = 12.8
    }
  }
}

extern "C" void kernel_launch(void* const* d_in, const int* in_sizes, int n_in,
                              void* d_out, int out_size, void* d_ws, size_t ws_size,
                              hipStream_t stream) {
  const float* feat_r = (const float*)d_in[1];  // feats_l contributes exactly C/D
  float* out = (float*)d_out;
  anynet_disp_kernel<<<dim3(kB * kH), dim3(kThreads), 0, stream>>>(feat_r, out);
}

// Round 9
// 17.265 us; speedup vs baseline: 1.0967x; 1.0967x over previous
//
#include <hip/hip_runtime.h>

namespace {
constexpr int kB   = 2;
constexpr int kC   = 64;
constexpr int kH   = 128;
constexpr int kW   = 240;
constexpr int kD0  = 16;          // disps 0,3,...,45
constexpr int kD1  = 5;           // disps -2,-1,0,1,2
constexpr int kWc1 = 285;
constexpr int kWc2 = 242;
constexpr int kPad = 48;          // left pad (>= max disp 45)
constexpr int kRow = 336;         // dwords per cpair row (48 pad |240 data |48 pad)
constexpr int kCP  = 32;          // channel pairs (64 channels)
constexpr int kGroups   = 3;      // cpair-parallel groups {11,11,10}
constexpr int kGThreads = 320;
constexpr int kThreads  = kGroups * kGThreads;  // 960 = 15 waves
constexpr int kAcc  = kD0 + kD1;  // 21
constexpr int kRStr = kWc1 * kAcc;             // 5985 floats per partial slot
constexpr int kOut1 = kB * kD0 * kH * kWc1;
constexpr int kN1   = kD0 * kWc1;              // 4560
constexpr int kN2   = kD1 * kWc2;              // 1210
typedef unsigned int v2u __attribute__((ext_vector_type(2)));
typedef float v2f __attribute__((ext_vector_type(2)));

__device__ __forceinline__ v2f UP(unsigned int x) {   // bf16x2 -> {lo,hi} f32
  v2f f;
  f.x = __uint_as_float(x << 16);
  f.y = __uint_as_float(x & 0xffff0000u);
  return f;
}
__device__ __forceinline__ unsigned int pk2(float lo, float hi) {
  unsigned int r;
  asm("v_cvt_pk_bf16_f32 %0, %1, %2" : "=v"(r) : "v"(lo), "v"(hi));
  return r;
}
__device__ __forceinline__ v2f pfma(v2f a, v2f b, v2f c) {
  return __builtin_elementwise_fma(a, b, c);   // -> v_pk_fma_f32
}
}

__global__ __launch_bounds__(kThreads)
void anynet_disp_kernel(const float* __restrict__ fr, float* __restrict__ out) {
  __shared__ unsigned int E[kCP * kRow];  // bf16x2 exp(feat_r): ch 2cp | 2cp+1
  __shared__ float P[kGroups * kRStr];    // dedicated partial slots
  const int bh  = blockIdx.x;             // 0..255
  const int b   = bh >> 7;
  const int h   = bh & 127;
  const int tid = threadIdx.x;

  // ---- phase A (MLP): issue all 4 global loads FIRST, pads under latency
  const float* fr_b = fr + (size_t)b * kC * kH * kW + (size_t)h * kW;
  const int i0 = tid, i1 = tid + kThreads;        // both < 1920
  const int cp0 = i0 / 60, xq0 = i0 % 60;
  const int cp1 = i1 / 60, xq1 = i1 % 60;
  const float4 a0 = *reinterpret_cast<const float4*>(
      fr_b + (size_t)(2 * cp0) * (kH * kW) + 4 * xq0);
  const float4 b0 = *reinterpret_cast<const float4*>(
      fr_b + (size_t)(2 * cp0 + 1) * (kH * kW) + 4 * xq0);
  const float4 a1 = *reinterpret_cast<const float4*>(
      fr_b + (size_t)(2 * cp1) * (kH * kW) + 4 * xq1);
  const float4 b1 = *reinterpret_cast<const float4*>(
      fr_b + (size_t)(2 * cp1 + 1) * (kH * kW) + 4 * xq1);
  // pad fill (independent of loads): bf16(1.0)x2 = exp(0), "invalid disparity"
  if (tid < kCP * 24) {
    const int cp = tid / 24, q = tid % 24;
    const int j4 = (q < 12) ? q : q + 60;         // uint4 [0,12) and [72,84)
    const uint4 ones = {0x3F803F80u, 0x3F803F80u, 0x3F803F80u, 0x3F803F80u};
    *reinterpret_cast<uint4*>(&E[cp * kRow + 4 * j4]) = ones;
  }
  // consume loads: exp + pack bf16 pairs
  {
    uint4 w0;
    w0.x = pk2(__expf(a0.x), __expf(b0.x));
    w0.y = pk2(__expf(a0.y), __expf(b0.y));
    w0.z = pk2(__expf(a0.z), __expf(b0.z));
    w0.w = pk2(__expf(a0.w), __expf(b0.w));
    *reinterpret_cast<uint4*>(&E[cp0 * kRow + kPad + 4 * xq0]) = w0;
    uint4 w1;
    w1.x = pk2(__expf(a1.x), __expf(b1.x));
    w1.y = pk2(__expf(a1.y), __expf(b1.y));
    w1.z = pk2(__expf(a1.z), __expf(b1.z));
    w1.w = pk2(__expf(a1.w), __expf(b1.w));
    *reinterpret_cast<uint4*>(&E[cp1 * kRow + kPad + 4 * xq1]) = w1;
  }
  __syncthreads();

  // ---- phase B: group g owns a cpair slice; thread col t. R7/R8's proven
  // 10x ds_read2_b32 tap fetch; all math in packed-f32 (v_pk_add/fma_f32).
  const int g = tid / kGThreads;      // 0..2
  const int t = tid % kGThreads;
  v2f acc1[kD0] = {};
  v2f acc2[kD1] = {};
  if (t < kWc1) {
    const int cbeg = (g == 0) ? 0 : (g == 1 ? 11 : 22);
    const int clen = (g < 2) ? 11 : 10;
    unsigned int addr = (unsigned int)(uintptr_t)(const void*)&E[cbeg * kRow + t + 3];
    for (int cc = 0; cc < clen; ++cc) {
      v2u p0, p1, p2, p3, p4, p5, p6, p7, q0, q1;
      asm volatile(
          "ds_read2_b32 %0, %10 offset0:45 offset1:42\n\t"
          "ds_read2_b32 %1, %10 offset0:39 offset1:36\n\t"
          "ds_read2_b32 %2, %10 offset0:33 offset1:30\n\t"
          "ds_read2_b32 %3, %10 offset0:27 offset1:24\n\t"
          "ds_read2_b32 %4, %10 offset0:21 offset1:18\n\t"
          "ds_read2_b32 %5, %10 offset0:15 offset1:12\n\t"
          "ds_read2_b32 %6, %10 offset0:9 offset1:6\n\t"
          "ds_read2_b32 %7, %10 offset0:3 offset1:0\n\t"
          "ds_read2_b32 %8, %10 offset0:43 offset1:44\n\t"
          "ds_read2_b32 %9, %10 offset0:46 offset1:47\n\t"
          "s_waitcnt lgkmcnt(0)"
          : "=&v"(p0), "=&v"(p1), "=&v"(p2), "=&v"(p3), "=&v"(p4),
            "=&v"(p5), "=&v"(p6), "=&v"(p7), "=&v"(q0), "=&v"(q1)
          : "v"(addr));
      // unpack taps: f[k] = {ch2cp, ch2cp+1} at D0 tap k (offset 45-3k)
      const v2f f0  = UP(p0.x), f1  = UP(p0.y), f2  = UP(p1.x), f3  = UP(p1.y);
      const v2f f4  = UP(p2.x), f5  = UP(p2.y), f6  = UP(p3.x), f7  = UP(p3.y);
      const v2f f8  = UP(p4.x), f9  = UP(p4.y), f10 = UP(p5.x), f11 = UP(p5.y);
      const v2f f12 = UP(p6.x), f13 = UP(p6.y), f14 = UP(p7.x), f15 = UP(p7.y);
      const v2f e0 = UP(q0.x), e1 = UP(q0.y);   // offs 43, 44
      const v2f e2 = UP(q1.x), e3 = UP(q1.y);   // offs 46, 47
      // D0 denominator (both channels at once): 15 v_pk_add_f32
      const v2f s = (((f0 + f1) + (f2 + f3)) + ((f4 + f5) + (f6 + f7))) +
                    (((f8 + f9) + (f10 + f11)) + ((f12 + f13) + (f14 + f15)));
      v2f r;
      r.x = __builtin_amdgcn_rcpf(s.x);
      r.y = __builtin_amdgcn_rcpf(s.y);
      acc1[0]  = pfma(f0,  r, acc1[0]);   acc1[1]  = pfma(f1,  r, acc1[1]);
      acc1[2]  = pfma(f2,  r, acc1[2]);   acc1[3]  = pfma(f3,  r, acc1[3]);
      acc1[4]  = pfma(f4,  r, acc1[4]);   acc1[5]  = pfma(f5,  r, acc1[5]);
      acc1[6]  = pfma(f6,  r, acc1[6]);   acc1[7]  = pfma(f7,  r, acc1[7]);
      acc1[8]  = pfma(f8,  r, acc1[8]);   acc1[9]  = pfma(f9,  r, acc1[9]);
      acc1[10] = pfma(f10, r, acc1[10]);  acc1[11] = pfma(f11, r, acc1[11]);
      acc1[12] = pfma(f12, r, acc1[12]);  acc1[13] = pfma(f13, r, acc1[13]);
      acc1[14] = pfma(f14, r, acc1[14]);  acc1[15] = pfma(f15, r, acc1[15]);
      // D1: taps at offs 47,46,45,44,43 = e3,e2,f0,e1,e0
      const v2f s2 = ((e0 + e1) + (e2 + e3)) + f0;
      v2f r2;
      r2.x = __builtin_amdgcn_rcpf(s2.x);
      r2.y = __builtin_amdgcn_rcpf(s2.y);
      acc2[0] = pfma(e3, r2, acc2[0]);
      acc2[1] = pfma(e2, r2, acc2[1]);
      acc2[2] = pfma(f0, r2, acc2[2]);
      acc2[3] = pfma(e1, r2, acc2[3]);
      acc2[4] = pfma(e0, r2, acc2[4]);
      addr += kRow * 4;
    }
  }
  __syncthreads();

  // ---- phase C: each group writes its OWN slot (disjoint, proven)
  if (t < kWc1) {
    float* __restrict__ R = &P[g * kRStr + t * kAcc];  // stride 21: conflict-free
    #pragma unroll
    for (int k = 0; k < kD0; ++k) R[k] = acc1[k].x + acc1[k].y;
    #pragma unroll
    for (int j = 0; j < kD1; ++j) R[kD0 + j] = acc2[j].x + acc2[j].y;
  }
  __syncthreads();

  // ---- phase D: combine 3 slots, coalesced writes (proven)
  for (int i = tid; i < kN1 + kN2; i += kThreads) {
    if (i < kN1) {
      const int d   = i / kWc1;
      const int col = i % kWc1;
      const int o   = col * kAcc + d;
      const float v = P[o] + P[kRStr + o] + P[2 * kRStr + o];
      out[((b * kD0 + d) * kH + h) * kWc1 + col] =
          (3.0f * (float)d) * (4.0f + v);              // C/D0 = 4
    } else {
      const int i2  = i - kN1;
      const int j   = i2 / kWc2;
      const int col = i2 % kWc2;
      const int o   = col * kAcc + kD0 + j;
      const float v = P[o] + P[kRStr + o] + P[2 * kRStr + o];
      out[kOut1 + ((b * kD1 + j) * kH + h) * kWc2 + col] =
          (float)(j - 2) * (64.0f / 5.0f + v);         // C/D1 = 12.8
    }
  }
}

extern "C" void kernel_launch(void* const* d_in, const int* in_sizes, int n_in,
                              void* d_out, int out_size, void* d_ws, size_t ws_size,
                              hipStream_t stream) {
  const float* feat_r = (const float*)d_in[1];  // feats_l contributes exactly C/D
  float* out = (float*)d_out;
  anynet_disp_kernel<<<dim3(kB * kH), dim3(kThreads), 0, stream>>>(feat_r, out);
}